// Round 1
// 246.374 us; speedup vs baseline: 1.0161x; 1.0161x over previous
//
#include <hip/hip_runtime.h>

#define N_NODES   100000
#define N_EDGES   600000
#define D_FEAT    128
#define N_CLASSES 64

typedef short bf16x8 __attribute__((ext_vector_type(8)));
typedef float f32x4  __attribute__((ext_vector_type(4)));
typedef unsigned short u16x8 __attribute__((ext_vector_type(8)));

__device__ __forceinline__ unsigned short f2bf(float f) {
    unsigned int u = __float_as_uint(f);
    unsigned int r = (u + 0x7fffu + ((u >> 16) & 1u)) >> 16;   // RNE
    return (unsigned short)r;
}
__device__ __forceinline__ float bf2f(unsigned short u) {
    return __uint_as_float((unsigned int)u << 16);
}

// ---------------------------------------------------------------------------
// Kernel 1: Wc[c][k] (128x128 bf16): c<64 -> Wu[c][k]=W[c*256+k],
//           c>=64 -> Wv[c-64][k]=W[(c-64)*256+128+k]
// ---------------------------------------------------------------------------
__global__ __launch_bounds__(256) void build_wcat(const float* __restrict__ W,
                                                  unsigned short* __restrict__ Wc) {
    int idx = blockIdx.x * 256 + threadIdx.x;   // 0..16383
    int c = idx >> 7;
    int k = idx & 127;
    float v = (c < 64) ? W[c * 256 + k] : W[(c - 64) * 256 + 128 + k];
    Wc[c * 128 + k] = f2bf(v);
}

// ---------------------------------------------------------------------------
// Kernel 2 (MFMA): P[n][c] = sum_k h[n][k]*Wc[c][k]  (+ b[c] for c<64), bf16 out
// A = Wc (M=channels), B = h (N=nodes):
//   A frag: ch = ct*16 + (lane&15), k = quad*8+j
//   B frag: node = n0 + (lane&15),  k = quad*8+j
//   D: row=channel = ct*16 + quad*4 + r, col=node = n0 + (lane&15)
// h loads are NONTEMPORAL (each row read exactly once; keep L2 clean for P).
// P stores are CACHED (edge_kernel gathers from L2/L3).
// ---------------------------------------------------------------------------
__global__ __launch_bounds__(256) void proj_mfma(const float* __restrict__ h,
                                                 const unsigned short* __restrict__ Wc,
                                                 const float* __restrict__ b,
                                                 unsigned short* __restrict__ P) {
    const int wave = (blockIdx.x * 256 + threadIdx.x) >> 6;
    const int lane = threadIdx.x & 63;
    const int n0   = wave * 16;                 // 100000 = 6250*16, no tail
    if (n0 >= N_NODES) return;
    const int m    = lane & 15;
    const int quad = lane >> 4;

    // B fragments: h[n0+m][ks*32 + quad*8 + 0..7], fp32 -> bf16 (NT loads)
    bf16x8 hfrag[4];
    const float* hrow = h + (size_t)(n0 + m) * 128 + quad * 8;
#pragma unroll
    for (int ks = 0; ks < 4; ++ks) {
        f32x4 v0 = __builtin_nontemporal_load((const f32x4*)(hrow + ks * 32));
        f32x4 v1 = __builtin_nontemporal_load((const f32x4*)(hrow + ks * 32 + 4));
        bf16x8 a;
        a[0] = (short)f2bf(v0[0]); a[1] = (short)f2bf(v0[1]);
        a[2] = (short)f2bf(v0[2]); a[3] = (short)f2bf(v0[3]);
        a[4] = (short)f2bf(v1[0]); a[5] = (short)f2bf(v1[1]);
        a[6] = (short)f2bf(v1[2]); a[7] = (short)f2bf(v1[3]);
        hfrag[ks] = a;
    }

    f32x4 acc[8];
#pragma unroll
    for (int ct = 0; ct < 8; ++ct) acc[ct] = (f32x4){0.f, 0.f, 0.f, 0.f};

#pragma unroll
    for (int ct = 0; ct < 8; ++ct) {
        const unsigned short* wrow = Wc + (size_t)(ct * 16 + m) * 128 + quad * 8;
#pragma unroll
        for (int ks = 0; ks < 4; ++ks) {
            bf16x8 wfrag = *(const bf16x8*)(wrow + ks * 32);
            acc[ct] = __builtin_amdgcn_mfma_f32_16x16x32_bf16(wfrag, hfrag[ks], acc[ct], 0, 0, 0);
        }
    }

    const int node = n0 + m;
    unsigned short* prow = P + (size_t)node * 128;
#pragma unroll
    for (int ct = 0; ct < 8; ++ct) {
        const int cb = ct * 16 + quad * 4;      // channel base, multiple of 4
        float v[4];
        if (cb < 64) {                          // fold bias into Wu half
            f32x4 bb = *(const f32x4*)(b + cb);
#pragma unroll
            for (int r = 0; r < 4; ++r) v[r] = acc[ct][r] + bb[r];
        } else {
#pragma unroll
            for (int r = 0; r < 4; ++r) v[r] = acc[ct][r];
        }
        ushort4 pk;
        pk.x = f2bf(v[0]); pk.y = f2bf(v[1]);
        pk.z = f2bf(v[2]); pk.w = f2bf(v[3]);
        *(ushort4*)(prow + cb) = pk;
    }
}

// ---------------------------------------------------------------------------
// Kernel 3: out[e][c] = P[src[e]][c] + P[dst[e]][64+c]   (bias already in P)
// 8 lanes/edge, 16B (ushort8) gather loads, 2x f32x4 nontemporal stores.
// Per edge: 16 loads + 16 stores (vs 48 mem-ops in the 16-lane version).
// ---------------------------------------------------------------------------
__global__ __launch_bounds__(256) void edge_kernel(const int* __restrict__ src,
                                                   const int* __restrict__ dst,
                                                   const unsigned short* __restrict__ P,
                                                   float* __restrict__ out) {
    int g  = blockIdx.x * 256 + threadIdx.x;    // exact grid: 600000*8
    int e  = g >> 3;
    int c0 = (g & 7) << 3;                      // 0,8,...,56
    int s = src[e];
    int d = dst[e];
    u16x8 us = *(const u16x8*)(P + (size_t)s * 128 + c0);
    u16x8 ud = *(const u16x8*)(P + (size_t)d * 128 + 64 + c0);
    f32x4 o0, o1;
    o0[0] = bf2f(us[0]) + bf2f(ud[0]);
    o0[1] = bf2f(us[1]) + bf2f(ud[1]);
    o0[2] = bf2f(us[2]) + bf2f(ud[2]);
    o0[3] = bf2f(us[3]) + bf2f(ud[3]);
    o1[0] = bf2f(us[4]) + bf2f(ud[4]);
    o1[1] = bf2f(us[5]) + bf2f(ud[5]);
    o1[2] = bf2f(us[6]) + bf2f(ud[6]);
    o1[3] = bf2f(us[7]) + bf2f(ud[7]);
    float* op = out + (size_t)e * 64 + c0;
    __builtin_nontemporal_store(o0, (f32x4*)op);
    __builtin_nontemporal_store(o1, (f32x4*)(op + 4));
}

// ---------------------------------------------------------------------------
// Fallback (ws too small): direct per-edge fp32 dot products.
// ---------------------------------------------------------------------------
__global__ __launch_bounds__(256) void direct_kernel(const float* __restrict__ h,
                                                     const int* __restrict__ src,
                                                     const int* __restrict__ dst,
                                                     const float* __restrict__ W,
                                                     const float* __restrict__ b,
                                                     float* __restrict__ out) {
    __shared__ float hcat[4][256];
    int t = threadIdx.x;
    int w = t >> 6, lane = t & 63;
    int e = blockIdx.x * 4 + w;
    bool valid = (e < N_EDGES);
    if (valid) {
        int s = src[e], d = dst[e];
        const float* p = (lane < 32) ? (h + (size_t)s * 128 + lane * 4)
                                     : (h + (size_t)d * 128 + (lane - 32) * 4);
        *(float4*)&hcat[w][lane * 4] = *(const float4*)p;
    }
    __syncthreads();
    if (!valid) return;
    int c = lane;
    float acc = 0.f;
    for (int k = 0; k < 256; k += 4) {
        float4 wv = *(const float4*)(W + c * 256 + k);
        acc += hcat[w][k] * wv.x + hcat[w][k + 1] * wv.y
             + hcat[w][k + 2] * wv.z + hcat[w][k + 3] * wv.w;
    }
    out[(size_t)e * 64 + c] = acc + b[c];
}

extern "C" void kernel_launch(void* const* d_in, const int* in_sizes, int n_in,
                              void* d_out, int out_size, void* d_ws, size_t ws_size,
                              hipStream_t stream) {
    const float* h   = (const float*)d_in[0];
    const int*   src = (const int*)d_in[1];
    const int*   dst = (const int*)d_in[2];
    const float* W   = (const float*)d_in[3];
    const float* b   = (const float*)d_in[4];
    float* out = (float*)d_out;

    const size_t wc_bytes = 128 * 128 * sizeof(unsigned short);              // 32 KiB
    const size_t p_bytes  = (size_t)N_NODES * 128 * sizeof(unsigned short);  // 25.6 MB
    if (ws_size >= wc_bytes + p_bytes) {
        unsigned short* Wc = (unsigned short*)d_ws;
        unsigned short* P  = (unsigned short*)((char*)d_ws + wc_bytes);
        build_wcat<<<64, 256, 0, stream>>>(W, Wc);
        const int n_waves  = N_NODES / 16;                                   // 6250
        const int n_blocks = (n_waves + 3) / 4;                              // 1563
        proj_mfma<<<n_blocks, 256, 0, stream>>>(h, Wc, b, P);
        edge_kernel<<<(N_EDGES * 8) / 256, 256, 0, stream>>>(src, dst, P, out);
    } else {
        direct_kernel<<<(N_EDGES + 3) / 4, 256, 0, stream>>>(h, src, dst, W, b, out);
    }
}

// Round 2
// 234.426 us; speedup vs baseline: 1.0678x; 1.0510x over previous
//
#include <hip/hip_runtime.h>

#define N_NODES   100000
#define N_EDGES   600000
#define D_FEAT    128
#define N_CLASSES 64

typedef short bf16x8 __attribute__((ext_vector_type(8)));
typedef float f32x4  __attribute__((ext_vector_type(4)));
typedef unsigned short u16x8 __attribute__((ext_vector_type(8)));

__device__ __forceinline__ unsigned short f2bf(float f) {
    unsigned int u = __float_as_uint(f);
    unsigned int r = (u + 0x7fffu + ((u >> 16) & 1u)) >> 16;   // RNE
    return (unsigned short)r;
}
__device__ __forceinline__ float bf2f(unsigned short u) {
    return __uint_as_float((unsigned int)u << 16);
}

// ---------------------------------------------------------------------------
// Kernel 1 (MFMA, fused Wc build): P[n][c] = sum_k h[n][k]*Wc[c][k]
//   (+ b[c] for c<64), bf16 out.
// Wc (128x128 bf16, 32 KiB) is built per-block in LDS from W:
//   c<64 -> Wu[c][k]=W[c*256+k], c>=64 -> Wv[c-64][k]=W[(c-64)*256+128+k]
// LDS rows are 256B => ds_read_b128 across 16 rows is a 16-way bank
// conflict; we store 16B chunks XOR-swizzled (chunk ^= row&15) => 2-way
// (free, m136). Build reads W from L2 (128 KiB, resident).
// A frag: ch = ct*16 + (lane&15), k = quad*8+j   (from LDS, swizzled)
// B frag: node = n0 + (lane&15),  k = quad*8+j   (from h, NT loads)
// D: row=channel = ct*16 + quad*4 + r, col=node = n0 + (lane&15)
// ---------------------------------------------------------------------------
__global__ __launch_bounds__(256) void proj_mfma(const float* __restrict__ h,
                                                 const float* __restrict__ W,
                                                 const float* __restrict__ b,
                                                 unsigned short* __restrict__ P) {
    __shared__ unsigned short WcS[128 * 128];   // 32 KiB, XOR-swizzled 16B chunks

    const int wave = (blockIdx.x * 256 + threadIdx.x) >> 6;
    const int lane = threadIdx.x & 63;
    const int n0   = wave * 16;                 // 100000 = 6250*16
    const bool valid = (n0 < N_NODES);          // only tail waves of last block invalid
    const int m    = lane & 15;
    const int quad = lane >> 4;

    // --- B fragments first: h[n0+m][ks*32 + quad*8 + 0..7], fp32 -> bf16 (NT).
    //     Issued before the LDS build so HBM latency hides under build VALU.
    bf16x8 hfrag[4];
    if (valid) {
        const float* hrow = h + (size_t)(n0 + m) * 128 + quad * 8;
#pragma unroll
        for (int ks = 0; ks < 4; ++ks) {
            f32x4 v0 = __builtin_nontemporal_load((const f32x4*)(hrow + ks * 32));
            f32x4 v1 = __builtin_nontemporal_load((const f32x4*)(hrow + ks * 32 + 4));
            bf16x8 a;
            a[0] = (short)f2bf(v0[0]); a[1] = (short)f2bf(v0[1]);
            a[2] = (short)f2bf(v0[2]); a[3] = (short)f2bf(v0[3]);
            a[4] = (short)f2bf(v1[0]); a[5] = (short)f2bf(v1[1]);
            a[6] = (short)f2bf(v1[2]); a[7] = (short)f2bf(v1[3]);
            hfrag[ks] = a;
        }
    }

    // --- Build Wc in LDS (all 256 threads; 16 f32x4 chunks each).
    {
        const int t = threadIdx.x;
#pragma unroll
        for (int i = 0; i < 16; ++i) {
            int cc = i * 256 + t;               // 0..4095 (4-elem chunks)
            int c  = cc >> 5;                   // row 0..127
            int kc = (cc & 31) << 2;            // ushort offset 0,4,...,124
            const float* wp = (c < 64) ? (W + c * 256 + kc)
                                       : (W + (c - 64) * 256 + 128 + kc);
            f32x4 v = *(const f32x4*)wp;
            ushort4 pk;
            pk.x = f2bf(v[0]); pk.y = f2bf(v[1]);
            pk.z = f2bf(v[2]); pk.w = f2bf(v[3]);
            int phys = (((kc >> 3) ^ (c & 15)) << 3) | (kc & 7);  // 16B-chunk XOR swizzle
            *(ushort4*)(WcS + c * 128 + phys) = pk;
        }
    }
    __syncthreads();
    if (!valid) return;

    f32x4 acc[8];
#pragma unroll
    for (int ct = 0; ct < 8; ++ct) acc[ct] = (f32x4){0.f, 0.f, 0.f, 0.f};

#pragma unroll
    for (int ct = 0; ct < 8; ++ct) {
        const unsigned short* wbase = WcS + (ct * 16 + m) * 128;
#pragma unroll
        for (int ks = 0; ks < 4; ++ks) {
            // logical chunk = ks*4+quad, row&15 = m  ->  phys chunk = chunk^m
            bf16x8 wfrag = *(const bf16x8*)(wbase + (((ks * 4 + quad) ^ m) << 3));
            acc[ct] = __builtin_amdgcn_mfma_f32_16x16x32_bf16(wfrag, hfrag[ks], acc[ct], 0, 0, 0);
        }
    }

    const int node = n0 + m;
    unsigned short* prow = P + (size_t)node * 128;
#pragma unroll
    for (int ct = 0; ct < 8; ++ct) {
        const int cb = ct * 16 + quad * 4;      // channel base, multiple of 4
        float v[4];
        if (cb < 64) {                          // fold bias into Wu half
            f32x4 bb = *(const f32x4*)(b + cb);
#pragma unroll
            for (int r = 0; r < 4; ++r) v[r] = acc[ct][r] + bb[r];
        } else {
#pragma unroll
            for (int r = 0; r < 4; ++r) v[r] = acc[ct][r];
        }
        ushort4 pk;
        pk.x = f2bf(v[0]); pk.y = f2bf(v[1]);
        pk.z = f2bf(v[2]); pk.w = f2bf(v[3]);
        *(ushort4*)(prow + cb) = pk;
    }
}

// ---------------------------------------------------------------------------
// Kernel 2: out[e][c] = P[src[e]][c] + P[dst[e]][64+c]   (bias already in P)
// 8 lanes/edge, 2 edges per lane (e and e+300000): 4 independent 16B
// gathers in flight per lane. f32x4 nontemporal stores.
// ---------------------------------------------------------------------------
__global__ __launch_bounds__(256) void edge_kernel(const int* __restrict__ src,
                                                   const int* __restrict__ dst,
                                                   const unsigned short* __restrict__ P,
                                                   float* __restrict__ out) {
    int g  = blockIdx.x * 256 + threadIdx.x;    // exact grid: 300000*8
    int e0 = g >> 3;
    int c0 = (g & 7) << 3;                      // 0,8,...,56
    int e1 = e0 + (N_EDGES / 2);
    int s0 = src[e0], d0 = dst[e0];
    int s1 = src[e1], d1 = dst[e1];
    u16x8 us0 = *(const u16x8*)(P + (size_t)s0 * 128 + c0);
    u16x8 ud0 = *(const u16x8*)(P + (size_t)d0 * 128 + 64 + c0);
    u16x8 us1 = *(const u16x8*)(P + (size_t)s1 * 128 + c0);
    u16x8 ud1 = *(const u16x8*)(P + (size_t)d1 * 128 + 64 + c0);

    f32x4 a0, a1, b0, b1;
#pragma unroll
    for (int j = 0; j < 4; ++j) {
        a0[j] = bf2f(us0[j])     + bf2f(ud0[j]);
        a1[j] = bf2f(us0[j + 4]) + bf2f(ud0[j + 4]);
        b0[j] = bf2f(us1[j])     + bf2f(ud1[j]);
        b1[j] = bf2f(us1[j + 4]) + bf2f(ud1[j + 4]);
    }
    float* op0 = out + (size_t)e0 * 64 + c0;
    float* op1 = out + (size_t)e1 * 64 + c0;
    __builtin_nontemporal_store(a0, (f32x4*)op0);
    __builtin_nontemporal_store(a1, (f32x4*)(op0 + 4));
    __builtin_nontemporal_store(b0, (f32x4*)op1);
    __builtin_nontemporal_store(b1, (f32x4*)(op1 + 4));
}

// ---------------------------------------------------------------------------
// Fallback (ws too small): direct per-edge fp32 dot products.
// ---------------------------------------------------------------------------
__global__ __launch_bounds__(256) void direct_kernel(const float* __restrict__ h,
                                                     const int* __restrict__ src,
                                                     const int* __restrict__ dst,
                                                     const float* __restrict__ W,
                                                     const float* __restrict__ b,
                                                     float* __restrict__ out) {
    __shared__ float hcat[4][256];
    int t = threadIdx.x;
    int w = t >> 6, lane = t & 63;
    int e = blockIdx.x * 4 + w;
    bool valid = (e < N_EDGES);
    if (valid) {
        int s = src[e], d = dst[e];
        const float* p = (lane < 32) ? (h + (size_t)s * 128 + lane * 4)
                                     : (h + (size_t)d * 128 + (lane - 32) * 4);
        *(float4*)&hcat[w][lane * 4] = *(const float4*)p;
    }
    __syncthreads();
    if (!valid) return;
    int c = lane;
    float acc = 0.f;
    for (int k = 0; k < 256; k += 4) {
        float4 wv = *(const float4*)(W + c * 256 + k);
        acc += hcat[w][k] * wv.x + hcat[w][k + 1] * wv.y
             + hcat[w][k + 2] * wv.z + hcat[w][k + 3] * wv.w;
    }
    out[(size_t)e * 64 + c] = acc + b[c];
}

extern "C" void kernel_launch(void* const* d_in, const int* in_sizes, int n_in,
                              void* d_out, int out_size, void* d_ws, size_t ws_size,
                              hipStream_t stream) {
    const float* h   = (const float*)d_in[0];
    const int*   src = (const int*)d_in[1];
    const int*   dst = (const int*)d_in[2];
    const float* W   = (const float*)d_in[3];
    const float* b   = (const float*)d_in[4];
    float* out = (float*)d_out;

    const size_t p_bytes = (size_t)N_NODES * 128 * sizeof(unsigned short);   // 25.6 MB
    if (ws_size >= p_bytes) {
        unsigned short* P = (unsigned short*)d_ws;
        const int n_waves  = N_NODES / 16;                                   // 6250
        const int n_blocks = (n_waves + 3) / 4;                              // 1563
        proj_mfma<<<n_blocks, 256, 0, stream>>>(h, W, b, P);
        edge_kernel<<<(N_EDGES / 2 * 8) / 256, 256, 0, stream>>>(src, dst, P, out);
    } else {
        direct_kernel<<<(N_EDGES + 3) / 4, 256, 0, stream>>>(h, src, dst, W, b, out);
    }
}